// Round 3
// baseline (444.511 us; speedup 1.0000x reference)
//
#include <hip/hip_runtime.h>

typedef __attribute__((ext_vector_type(8))) short short8;
typedef __attribute__((ext_vector_type(4))) float floatx4;

#define LSTR 40  // LDS row stride in shorts: 32 data + 8 pad = 80 B (16B-aligned)

__device__ __forceinline__ float b2f(unsigned short u) {
  return __uint_as_float(((unsigned int)u) << 16);
}
__device__ __forceinline__ unsigned short f2b(float f) {
  unsigned int u = __float_as_uint(f);
  unsigned int r = (u + 0x7FFFu + ((u >> 16) & 1u)) >> 16;  // RNE
  return (unsigned short)r;
}
// load 8 fp32, convert to 8 bf16 packed in a uint4
__device__ __forceinline__ uint4 ld8f(const float* p) {
  float4 a = *(const float4*)p;
  float4 b = *(const float4*)(p + 4);
  uint4 r;
  r.x = (unsigned int)f2b(a.x) | ((unsigned int)f2b(a.y) << 16);
  r.y = (unsigned int)f2b(a.z) | ((unsigned int)f2b(a.w) << 16);
  r.z = (unsigned int)f2b(b.x) | ((unsigned int)f2b(b.y) << 16);
  r.w = (unsigned int)f2b(b.z) | ((unsigned int)f2b(b.w) << 16);
  return r;
}

// C[M,N] = act(A[M,K] @ Bt[N,K]^T + bias). A fp32 or bf16 (AF32), C fp32 or bf16 (CF32).
// B always bf16. fp32 accumulate. arow = optional A row indirection (embedding gather).
template<int AF32, int CF32, int ACT>
__global__ __launch_bounds__(256, 2) void gemm_bt(
    const void* __restrict__ Av,
    const unsigned short* __restrict__ Bt,
    const float* __restrict__ bias,
    void* __restrict__ Cv,
    const int* __restrict__ arow,
    int M, int N, int K,
    long aBatch, long bBatch, long cBatch)
{
  __shared__ unsigned short ldsA[128 * LSTR];
  __shared__ unsigned short ldsB[128 * LSTR];

  const int b = blockIdx.z;
  const unsigned short* Ab16 = (const unsigned short*)Av + (size_t)b * aBatch;
  const float*          Ab32 = (const float*)Av          + (size_t)b * aBatch;
  const unsigned short* Bb = Bt + (size_t)b * bBatch;

  const int m0 = blockIdx.y * 128, n0 = blockIdx.x * 128;
  const int tid = threadIdx.x;
  const int wave = tid >> 6, lane = tid & 63;
  const int quad = lane >> 4, l16 = lane & 15;
  const int wy = wave >> 1, wx = wave & 1;
  const int r0 = tid >> 2;        // staging row 0..63 (and +64)
  const int s0 = (tid & 3) * 8;   // staging col offset (8-elem chunks)

  floatx4 acc[4][4];
#pragma unroll
  for (int i = 0; i < 4; i++)
#pragma unroll
    for (int j = 0; j < 4; j++)
      acc[i][j] = (floatx4){0.f, 0.f, 0.f, 0.f};

  size_t ra0, ra1;
  {
    int gm0 = m0 + r0, gm1 = gm0 + 64;
    ra0 = arow ? (size_t)arow[gm0] : (size_t)gm0;
    ra1 = arow ? (size_t)arow[gm1] : (size_t)gm1;
  }
  const size_t rb0 = (size_t)(n0 + r0), rb1 = rb0 + 64;

  for (int k0 = 0; k0 < K; k0 += 32) {
    uint4 av0, av1;
    if (AF32) {
      av0 = ld8f(Ab32 + ra0 * K + k0 + s0);
      av1 = ld8f(Ab32 + ra1 * K + k0 + s0);
    } else {
      av0 = *(const uint4*)(Ab16 + ra0 * K + k0 + s0);
      av1 = *(const uint4*)(Ab16 + ra1 * K + k0 + s0);
    }
    uint4 bv0 = *(const uint4*)(Bb + rb0 * K + k0 + s0);
    uint4 bv1 = *(const uint4*)(Bb + rb1 * K + k0 + s0);
    __syncthreads();  // previous iter's frag reads done before overwrite
    *(uint4*)&ldsA[r0 * LSTR + s0] = av0;
    *(uint4*)&ldsA[(r0 + 64) * LSTR + s0] = av1;
    *(uint4*)&ldsB[r0 * LSTR + s0] = bv0;
    *(uint4*)&ldsB[(r0 + 64) * LSTR + s0] = bv1;
    __syncthreads();

    short8 af[4], bfr[4];
#pragma unroll
    for (int i = 0; i < 4; i++)
      af[i] = *(const short8*)&ldsA[(wy * 64 + i * 16 + l16) * LSTR + quad * 8];
#pragma unroll
    for (int j = 0; j < 4; j++)
      bfr[j] = *(const short8*)&ldsB[(wx * 64 + j * 16 + l16) * LSTR + quad * 8];
#pragma unroll
    for (int i = 0; i < 4; i++)
#pragma unroll
      for (int j = 0; j < 4; j++)
        acc[i][j] = __builtin_amdgcn_mfma_f32_16x16x32_bf16(af[i], bfr[j], acc[i][j], 0, 0, 0);
  }

  float bv[4];
#pragma unroll
  for (int j = 0; j < 4; j++) {
    int n = n0 + wx * 64 + j * 16 + l16;
    bv[j] = bias ? bias[n] : 0.f;
  }
  float*          Cf = (float*)Cv          + (size_t)b * cBatch;
  unsigned short* Ch = (unsigned short*)Cv + (size_t)b * cBatch;
#pragma unroll
  for (int i = 0; i < 4; i++) {
#pragma unroll
    for (int r = 0; r < 4; r++) {
      int m = m0 + wy * 64 + i * 16 + quad * 4 + r;
      size_t base = (size_t)m * N + (n0 + wx * 64 + l16);
#pragma unroll
      for (int j = 0; j < 4; j++) {
        float v = acc[i][j][r] + bv[j];
        if (ACT == 1) v = tanhf(v);
        if (CF32) Cf[base + j * 16] = v;
        else      Ch[base + j * 16] = f2b(v);
      }
    }
  }
}

// E[b,m,n] = dep==0 ? 0 : exp(clamp((q_m . k_n) * dep_table[dep]))  -- unnormalized, fp32 out
__global__ __launch_bounds__(256, 2) void score_kernel(
    const unsigned short* __restrict__ Q,
    const unsigned short* __restrict__ Kmat,
    const int* __restrict__ dep,
    const float* __restrict__ dep_table,
    float* __restrict__ E)
{
  __shared__ unsigned short ldsA[128 * LSTR];
  __shared__ unsigned short ldsB[128 * LSTR];
  __shared__ float dtab[64];

  const int tid = threadIdx.x;
  if (tid < 64) dtab[tid] = dep_table[tid];

  const int b = blockIdx.z;
  const unsigned short* Ab = Q + (size_t)b * (1024 * 512);
  const unsigned short* Bb = Kmat + (size_t)b * (1024 * 512);

  const int m0 = blockIdx.y * 128, n0 = blockIdx.x * 128;
  const int wave = tid >> 6, lane = tid & 63;
  const int quad = lane >> 4, l16 = lane & 15;
  const int wy = wave >> 1, wx = wave & 1;
  const int r0 = tid >> 2, s0 = (tid & 3) * 8;

  floatx4 acc[4][4];
#pragma unroll
  for (int i = 0; i < 4; i++)
#pragma unroll
    for (int j = 0; j < 4; j++)
      acc[i][j] = (floatx4){0.f, 0.f, 0.f, 0.f};

  for (int k0 = 0; k0 < 512; k0 += 32) {
    uint4 av0 = *(const uint4*)(Ab + (size_t)(m0 + r0) * 512 + k0 + s0);
    uint4 av1 = *(const uint4*)(Ab + (size_t)(m0 + r0 + 64) * 512 + k0 + s0);
    uint4 bv0 = *(const uint4*)(Bb + (size_t)(n0 + r0) * 512 + k0 + s0);
    uint4 bv1 = *(const uint4*)(Bb + (size_t)(n0 + r0 + 64) * 512 + k0 + s0);
    __syncthreads();
    *(uint4*)&ldsA[r0 * LSTR + s0] = av0;
    *(uint4*)&ldsA[(r0 + 64) * LSTR + s0] = av1;
    *(uint4*)&ldsB[r0 * LSTR + s0] = bv0;
    *(uint4*)&ldsB[(r0 + 64) * LSTR + s0] = bv1;
    __syncthreads();

    short8 af[4], bfr[4];
#pragma unroll
    for (int i = 0; i < 4; i++)
      af[i] = *(const short8*)&ldsA[(wy * 64 + i * 16 + l16) * LSTR + quad * 8];
#pragma unroll
    for (int j = 0; j < 4; j++)
      bfr[j] = *(const short8*)&ldsB[(wx * 64 + j * 16 + l16) * LSTR + quad * 8];
#pragma unroll
    for (int i = 0; i < 4; i++)
#pragma unroll
      for (int j = 0; j < 4; j++)
        acc[i][j] = __builtin_amdgcn_mfma_f32_16x16x32_bf16(af[i], bfr[j], acc[i][j], 0, 0, 0);
  }

  const int* depb = dep + (size_t)b * 1024 * 1024;
  float* Eb = E + (size_t)b * 1024 * 1024;
#pragma unroll
  for (int i = 0; i < 4; i++) {
#pragma unroll
    for (int r = 0; r < 4; r++) {
      int m = m0 + wy * 64 + i * 16 + quad * 4 + r;
      const int* drow = depb + (size_t)m * 1024 + (n0 + wx * 64 + l16);
      float* erow = Eb + (size_t)m * 1024 + (n0 + wx * 64 + l16);
#pragma unroll
      for (int j = 0; j < 4; j++) {
        int d = drow[j * 16];
        float s = fminf(fmaxf(acc[i][j][r] * dtab[d & 63], -60.f), 60.f);
        erow[j * 16] = d ? __expf(s) : 0.f;
      }
    }
  }
}

// out[c][r] = bf16(in[r][c]); input fp32 (INF32=1) or bf16 (INF32=0); batched
template<int INF32>
__global__ void transpose_to_bf16(const void* __restrict__ in,
                                  unsigned short* __restrict__ out,
                                  int R, int C, long inB, long outB)
{
  __shared__ unsigned short tile[32][33];
  unsigned short* ob = out + (size_t)blockIdx.z * outB;
  int c0 = blockIdx.x * 32, r0 = blockIdx.y * 32;
  int tx = threadIdx.x & 31, ty = threadIdx.x >> 5;
  if (INF32) {
    const float* ib = (const float*)in + (size_t)blockIdx.z * inB;
    for (int i = ty; i < 32; i += 8)
      tile[i][tx] = f2b(ib[(size_t)(r0 + i) * C + (c0 + tx)]);
  } else {
    const unsigned short* ib = (const unsigned short*)in + (size_t)blockIdx.z * inB;
    for (int i = ty; i < 32; i += 8)
      tile[i][tx] = ib[(size_t)(r0 + i) * C + (c0 + tx)];
  }
  __syncthreads();
  for (int i = ty; i < 32; i += 8)
    ob[(size_t)(c0 + i) * R + (r0 + tx)] = tile[tx][i];
}

// one block per row: w[row][:] /= sum(w[row][:])   (1024 fp32 per row)
__global__ void normalize_rows(float* __restrict__ w)
{
  size_t row = blockIdx.x;
  float4* p = (float4*)(w + row * 1024);
  float4 u = p[threadIdx.x];
  float s = (u.x + u.y) + (u.z + u.w);
#pragma unroll
  for (int d = 1; d < 64; d <<= 1) s += __shfl_xor(s, d);
  __shared__ float acc4[4];
  int wave = threadIdx.x >> 6;
  if ((threadIdx.x & 63) == 0) acc4[wave] = s;
  __syncthreads();
  float tot = (acc4[0] + acc4[1]) + (acc4[2] + acc4[3]);
  float inv = tot > 0.f ? 1.f / tot : 0.f;
  u.x *= inv; u.y *= inv; u.z *= inv; u.w *= inv;
  p[threadIdx.x] = u;
}

extern "C" void kernel_launch(void* const* d_in, const int* in_sizes, int n_in,
                              void* d_out, int out_size, void* d_ws, size_t ws_size,
                              hipStream_t stream)
{
  const int*   inputs     = (const int*)d_in[0];
  const int*   dependency = (const int*)d_in[1];
  const float* embed      = (const float*)d_in[2];
  const float* dept       = (const float*)d_in[3];
  const float* Wq = (const float*)d_in[4];   const float* bq = (const float*)d_in[5];
  const float* Wk = (const float*)d_in[6];   const float* bk = (const float*)d_in[7];
  const float* Wv = (const float*)d_in[8];   const float* bvv = (const float*)d_in[9];
  const float* W1 = (const float*)d_in[10];  const float* b1 = (const float*)d_in[11];
  const float* W2 = (const float*)d_in[12];  const float* b2 = (const float*)d_in[13];

  float* out  = (float*)d_out;                       // wm [16,1024,512] fp32
  float* wout = out + (size_t)16 * 1024 * 512;       // weights [16,1024,1024] fp32

  // ws (bf16 intermediates), high-water ~36 MB, aliased by liveness:
  unsigned short* ws  = (unsigned short*)d_ws;
  unsigned short* q   = ws;                   // [16384,512] bf16 (later vT, then h)
  unsigned short* kx  = ws + 8388608;         // [16384,512] bf16 (later wmp)
  unsigned short* WqT = ws + 16777216;        // 5 x [512,512] bf16
  unsigned short* WkT = WqT + 262144;
  unsigned short* WvT = WkT + 262144;
  unsigned short* W1T = WvT + 262144;
  unsigned short* W2T = W1T + 262144;
  unsigned short* v   = (unsigned short*)out; // bf16 v staged in wm region (16 MB of 32 MB)
  unsigned short* vT  = q;
  unsigned short* wmp = kx;
  unsigned short* h   = q;

  dim3 blk(256);

  transpose_to_bf16<1><<<dim3(16, 16, 1), blk, 0, stream>>>(Wq, WqT, 512, 512, 0, 0);
  transpose_to_bf16<1><<<dim3(16, 16, 1), blk, 0, stream>>>(Wk, WkT, 512, 512, 0, 0);
  transpose_to_bf16<1><<<dim3(16, 16, 1), blk, 0, stream>>>(Wv, WvT, 512, 512, 0, 0);
  transpose_to_bf16<1><<<dim3(16, 16, 1), blk, 0, stream>>>(W1, W1T, 512, 512, 0, 0);
  transpose_to_bf16<1><<<dim3(16, 16, 1), blk, 0, stream>>>(W2, W2T, 512, 512, 0, 0);

  // q/k/v = bf16(embed[inputs] @ W^T + b)   (gather fused; A fp32 -> bf16 in staging)
  gemm_bt<1,0,0><<<dim3(4, 128, 1), blk, 0, stream>>>(embed, WqT, bq, q, inputs, 16384, 512, 512, 0, 0, 0);
  gemm_bt<1,0,0><<<dim3(4, 128, 1), blk, 0, stream>>>(embed, WkT, bk, kx, inputs, 16384, 512, 512, 0, 0, 0);
  gemm_bt<1,0,0><<<dim3(4, 128, 1), blk, 0, stream>>>(embed, WvT, bvv, v, inputs, 16384, 512, 512, 0, 0, 0);

  // unnormalized exp-scores (fp32) straight into the weights output region
  score_kernel<<<dim3(8, 8, 16), blk, 0, stream>>>(q, kx, dependency, dept, wout);

  // q dead -> vT overwrites it
  transpose_to_bf16<0><<<dim3(16, 32, 16), blk, 0, stream>>>(v, vT, 1024, 512, 1024L * 512, 512L * 1024);

  normalize_rows<<<dim3(16384), blk, 0, stream>>>(wout);

  // wm_pre[b] = bf16(weights[b] @ v[b])   (A fp32 weights; kx dead -> wmp)
  gemm_bt<1,0,0><<<dim3(4, 8, 16), blk, 0, stream>>>(wout, vT, nullptr, wmp, nullptr,
                                                     1024, 512, 1024, 1024L * 1024, 512L * 1024, 1024L * 512);
  // h = bf16(tanh(wm_pre @ W1^T + b1))   (vT dead -> h)
  gemm_bt<0,0,1><<<dim3(4, 128, 1), blk, 0, stream>>>(wmp, W1T, b1, h, nullptr, 16384, 512, 512, 0, 0, 0);
  // wm = fp32(h @ W2^T + b2)  (overwrites v staging; v dead)
  gemm_bt<0,1,0><<<dim3(4, 128, 1), blk, 0, stream>>>(h, W2T, b2, out, nullptr, 16384, 512, 512, 0, 0, 0);
}

// Round 4
// 404.977 us; speedup vs baseline: 1.0976x; 1.0976x over previous
//
#include <hip/hip_runtime.h>

typedef __attribute__((ext_vector_type(8))) short short8;
typedef __attribute__((ext_vector_type(4))) float floatx4;

__device__ __forceinline__ unsigned short f2b(float f) {
  unsigned int u = __float_as_uint(f);
  unsigned int r = (u + 0x7FFFu + ((u >> 16) & 1u)) >> 16;  // RNE
  return (unsigned short)r;
}
// load 8 fp32, convert to 8 bf16 packed in a uint4
__device__ __forceinline__ uint4 ld8f(const float* p) {
  float4 a = *(const float4*)p;
  float4 b = *(const float4*)(p + 4);
  uint4 r;
  r.x = (unsigned int)f2b(a.x) | ((unsigned int)f2b(a.y) << 16);
  r.y = (unsigned int)f2b(a.z) | ((unsigned int)f2b(a.w) << 16);
  r.z = (unsigned int)f2b(b.x) | ((unsigned int)f2b(b.y) << 16);
  r.w = (unsigned int)f2b(b.z) | ((unsigned int)f2b(b.w) << 16);
  return r;
}

// async global->LDS, 16B per lane (m97: the 874 TF staging path)
#define GLL(g, l) __builtin_amdgcn_global_load_lds( \
    (const __attribute__((address_space(1))) unsigned int*)(g), \
    (__attribute__((address_space(3))) unsigned int*)(l), 16, 0, 0)

// m97-style K-loop: 128x128 tile, BK=32, unpadded LDS stride 32 shorts,
// global_load_lds staging, 16x16x32 bf16 MFMA, 2x2 waves x 4x4 frags.
// A,B pre-offset to (m0,n0) tile row bases; both bf16 row-major [*,K].
__device__ __forceinline__ void kloop(const unsigned short* __restrict__ A,
                                      const unsigned short* __restrict__ B,
                                      int K, unsigned short* ldsA, unsigned short* ldsB,
                                      floatx4 (&acc)[4][4])
{
  const int tid = threadIdx.x;
  const int w = tid >> 6, lane = tid & 63;
  const int quad = lane >> 4, l16 = lane & 15;
  const int wy = w >> 1, wx = w & 1;
  const int rs = 32 * w + (lane >> 2);       // staging row (and +16 for 2nd inst)
  const int ks = (lane & 3) * 8;             // staging k-offset (shorts)
  const int lo0 = (w * 2) * 512 + lane * 8;  // LDS dest (shorts): wave-uniform + lane*16B
  const int lo1 = lo0 + 512;
  const unsigned short* a0 = A + (size_t)rs * K + ks;
  const unsigned short* a1 = a0 + (size_t)16 * K;
  const unsigned short* b0 = B + (size_t)rs * K + ks;
  const unsigned short* b1 = b0 + (size_t)16 * K;

  for (int k0 = 0; k0 < K; k0 += 32) {
    __syncthreads();                 // prior iter's frag reads done
    GLL(a0 + k0, &ldsA[lo0]);
    GLL(a1 + k0, &ldsA[lo1]);
    GLL(b0 + k0, &ldsB[lo0]);
    GLL(b1 + k0, &ldsB[lo1]);
    __syncthreads();                 // drains vmcnt -> LDS ready
    short8 af[4], bf[4];
#pragma unroll
    for (int i = 0; i < 4; i++)
      af[i] = *(const short8*)&ldsA[(wy * 64 + i * 16 + l16) * 32 + quad * 8];
#pragma unroll
    for (int j = 0; j < 4; j++)
      bf[j] = *(const short8*)&ldsB[(wx * 64 + j * 16 + l16) * 32 + quad * 8];
#pragma unroll
    for (int i = 0; i < 4; i++)
#pragma unroll
      for (int j = 0; j < 4; j++)
        acc[i][j] = __builtin_amdgcn_mfma_f32_16x16x32_bf16(af[i], bf[j], acc[i][j], 0, 0, 0);
  }
}

// ---- fused QKV: C[16384,1536] split into q/k/v [16384,512] each, bias per segment
__global__ __launch_bounds__(256, 2) void gemm_qkv(
    const unsigned short* __restrict__ x,   // [16384,512] bf16
    const unsigned short* __restrict__ WT,  // [1536,512] bf16 (Wq^T;Wk^T;Wv^T)
    const float* __restrict__ bq, const float* __restrict__ bk, const float* __restrict__ bv,
    unsigned short* __restrict__ q, unsigned short* __restrict__ kx, unsigned short* __restrict__ v)
{
  __shared__ unsigned short ldsA[4096], ldsB[4096];
  const int m0 = blockIdx.y * 128, n0 = blockIdx.x * 128;
  floatx4 acc[4][4];
#pragma unroll
  for (int i = 0; i < 4; i++)
#pragma unroll
    for (int j = 0; j < 4; j++) acc[i][j] = (floatx4){0.f, 0.f, 0.f, 0.f};

  kloop(x + (size_t)m0 * 512, WT + (size_t)n0 * 512, 512, ldsA, ldsB, acc);

  const int seg = n0 >> 9, nloc = n0 & 511;
  unsigned short* C = seg == 0 ? q : (seg == 1 ? kx : v);
  const float* bias = seg == 0 ? bq : (seg == 1 ? bk : bv);
  const int lane = threadIdx.x & 63, w = threadIdx.x >> 6;
  const int quad = lane >> 4, l16 = lane & 15, wy = w >> 1, wx = w & 1;
  float bvv[4];
#pragma unroll
  for (int j = 0; j < 4; j++) bvv[j] = bias[nloc + wx * 64 + j * 16 + l16];
#pragma unroll
  for (int i = 0; i < 4; i++)
#pragma unroll
    for (int r = 0; r < 4; r++) {
      int m = m0 + wy * 64 + i * 16 + quad * 4 + r;
      unsigned short* crow = C + (size_t)m * 512 + nloc + wx * 64 + l16;
#pragma unroll
      for (int j = 0; j < 4; j++) crow[j * 16] = f2b(acc[i][j][r] + bvv[j]);
    }
}

// ---- generic bf16 GEMM: C = act(A @ Bt^T + bias), C fp32 (CF32) or bf16
template<int CF32, int ACT>
__global__ __launch_bounds__(256, 2) void gemm2(
    const unsigned short* __restrict__ A, const unsigned short* __restrict__ Bt,
    const float* __restrict__ bias, void* __restrict__ Cv,
    int N, int K, long aB, long bB, long cB)
{
  __shared__ unsigned short ldsA[4096], ldsB[4096];
  const int b = blockIdx.z;
  const int m0 = blockIdx.y * 128, n0 = blockIdx.x * 128;
  floatx4 acc[4][4];
#pragma unroll
  for (int i = 0; i < 4; i++)
#pragma unroll
    for (int j = 0; j < 4; j++) acc[i][j] = (floatx4){0.f, 0.f, 0.f, 0.f};

  kloop(A + (size_t)b * aB + (size_t)m0 * K, Bt + (size_t)b * bB + (size_t)n0 * K,
        K, ldsA, ldsB, acc);

  const int lane = threadIdx.x & 63, w = threadIdx.x >> 6;
  const int quad = lane >> 4, l16 = lane & 15, wy = w >> 1, wx = w & 1;
  float bvv[4];
#pragma unroll
  for (int j = 0; j < 4; j++)
    bvv[j] = bias ? bias[n0 + wx * 64 + j * 16 + l16] : 0.f;
  float*          Cf = (float*)Cv          + (size_t)b * cB;
  unsigned short* Ch = (unsigned short*)Cv + (size_t)b * cB;
#pragma unroll
  for (int i = 0; i < 4; i++)
#pragma unroll
    for (int r = 0; r < 4; r++) {
      int m = m0 + wy * 64 + i * 16 + quad * 4 + r;
      size_t base = (size_t)m * N + n0 + wx * 64 + l16;
#pragma unroll
      for (int j = 0; j < 4; j++) {
        float vv = acc[i][j][r] + bvv[j];
        if (ACT == 1) vv = tanhf(vv);
        if (CF32) Cf[base + j * 16] = vv;
        else      Ch[base + j * 16] = f2b(vv);
      }
    }
}

// ---- score: E = dep ? exp(clamp((q.k)*dtab[dep])) : 0, fp32, coalesced epilogue
#define CST 132  // padded fp32 tile stride (floats): breaks row-bank aliasing
__global__ __launch_bounds__(256, 2) void score_kernel(
    const unsigned short* __restrict__ Q, const unsigned short* __restrict__ Km,
    const int* __restrict__ dep, const float* __restrict__ dept,
    float* __restrict__ E)
{
  __shared__ union {
    struct { unsigned short a[4096]; unsigned short b[4096]; } s;
    float c[32 * CST];
  } sm;
  __shared__ float dtab[64];
  const int tid = threadIdx.x;
  if (tid < 64) dtab[tid] = dept[tid];

  const int b = blockIdx.z;
  const int m0 = blockIdx.y * 128, n0 = blockIdx.x * 128;
  floatx4 acc[4][4];
#pragma unroll
  for (int i = 0; i < 4; i++)
#pragma unroll
    for (int j = 0; j < 4; j++) acc[i][j] = (floatx4){0.f, 0.f, 0.f, 0.f};

  kloop(Q + (size_t)b * (1024 * 512) + (size_t)m0 * 512,
        Km + (size_t)b * (1024 * 512) + (size_t)n0 * 512,
        512, sm.s.a, sm.s.b, acc);

  const int lane = tid & 63, w = tid >> 6;
  const int quad = lane >> 4, l16 = lane & 15, wy = w >> 1, wx = w & 1;
  const int* depb = dep + (size_t)b * 1024 * 1024;
  float* Eb = E + (size_t)b * 1024 * 1024;
  const int cr = tid >> 3, cb = (tid & 7) * 16;

#pragma unroll
  for (int i = 0; i < 4; i++) {
    __syncthreads();  // LDS free (prior frag reads / prior i's tile reads done)
#pragma unroll
    for (int j = 0; j < 4; j++)
#pragma unroll
      for (int r = 0; r < 4; r++)
        sm.c[(wy * 16 + quad * 4 + r) * CST + wx * 64 + j * 16 + l16] = acc[i][j][r];
    __syncthreads();
    // 32 rows x 128 cols; thread: row cr, 16 cols at cb -- all 16B accesses
    const int m = m0 + (cr >> 4) * 64 + i * 16 + (cr & 15);
    const int* dr = depb + (size_t)m * 1024 + n0 + cb;
    float* er = Eb + (size_t)m * 1024 + n0 + cb;
    const float* crow = &sm.c[cr * CST + cb];
#pragma unroll
    for (int c = 0; c < 4; c++) {
      int4 d = *(const int4*)(dr + c * 4);
      float4 s = *(const float4*)(crow + c * 4);
      float4 e;
      e.x = d.x ? __expf(fminf(fmaxf(s.x * dtab[d.x & 63], -60.f), 60.f)) : 0.f;
      e.y = d.y ? __expf(fminf(fmaxf(s.y * dtab[d.y & 63], -60.f), 60.f)) : 0.f;
      e.z = d.z ? __expf(fminf(fmaxf(s.z * dtab[d.z & 63], -60.f), 60.f)) : 0.f;
      e.w = d.w ? __expf(fminf(fmaxf(s.w * dtab[d.w & 63], -60.f), 60.f)) : 0.f;
      *(float4*)(er + c * 4) = e;
    }
  }
}

// ---- x = bf16(embed[inputs]) : one row per 64 lanes, 4 rows/block
__global__ void build_x(const float* __restrict__ embed, const int* __restrict__ inputs,
                        unsigned short* __restrict__ x)
{
  const int row = blockIdx.x * 4 + (threadIdx.x >> 6);
  const int lane = threadIdx.x & 63;
  const float* src = embed + (size_t)inputs[row] * 512 + lane * 8;
  *(uint4*)&x[(size_t)row * 512 + lane * 8] = ld8f(src);
}

// ---- all 5 weight transposes fp32->bf16 in one launch (z selects source)
__global__ void trans_w(const float* s0, const float* s1, const float* s2,
                        const float* s3, const float* s4, unsigned short* dst)
{
  __shared__ unsigned short tile[32][33];
  const int z = blockIdx.z;
  const float* src = z == 0 ? s0 : z == 1 ? s1 : z == 2 ? s2 : z == 3 ? s3 : s4;
  unsigned short* ob = dst + (size_t)z * 262144;
  int c0 = blockIdx.x * 32, r0 = blockIdx.y * 32;
  int tx = threadIdx.x & 31, ty = threadIdx.x >> 5;
  for (int i = ty; i < 32; i += 8)
    tile[i][tx] = f2b(src[(size_t)(r0 + i) * 512 + (c0 + tx)]);
  __syncthreads();
  for (int i = ty; i < 32; i += 8)
    ob[(size_t)(c0 + i) * 512 + (r0 + tx)] = tile[tx][i];
}

// ---- bf16 transpose (v -> vT), batched
__global__ void trans_v(const unsigned short* __restrict__ in, unsigned short* __restrict__ out)
{
  __shared__ unsigned short tile[32][33];
  const unsigned short* ib = in + (size_t)blockIdx.z * (1024 * 512);
  unsigned short* ob = out + (size_t)blockIdx.z * (512 * 1024);
  int c0 = blockIdx.x * 32, r0 = blockIdx.y * 32;
  int tx = threadIdx.x & 31, ty = threadIdx.x >> 5;
  for (int i = ty; i < 32; i += 8)
    tile[i][tx] = ib[(size_t)(r0 + i) * 512 + (c0 + tx)];
  __syncthreads();
  for (int i = ty; i < 32; i += 8)
    ob[(size_t)(c0 + i) * 1024 + (r0 + tx)] = tile[tx][i];
}

// ---- rows /= rowsum; also emit bf16 copy for the PV GEMM
__global__ void normalize_rows(float* __restrict__ wf, unsigned short* __restrict__ wb)
{
  size_t row = blockIdx.x;
  float4* p = (float4*)(wf + row * 1024);
  float4 u = p[threadIdx.x];
  float s = (u.x + u.y) + (u.z + u.w);
#pragma unroll
  for (int d = 1; d < 64; d <<= 1) s += __shfl_xor(s, d);
  __shared__ float acc4[4];
  if ((threadIdx.x & 63) == 0) acc4[threadIdx.x >> 6] = s;
  __syncthreads();
  float tot = (acc4[0] + acc4[1]) + (acc4[2] + acc4[3]);
  float inv = tot > 0.f ? 1.f / tot : 0.f;
  u.x *= inv; u.y *= inv; u.z *= inv; u.w *= inv;
  p[threadIdx.x] = u;
  uint2 pk;
  pk.x = (unsigned int)f2b(u.x) | ((unsigned int)f2b(u.y) << 16);
  pk.y = (unsigned int)f2b(u.z) | ((unsigned int)f2b(u.w) << 16);
  *(uint2*)&wb[row * 1024 + threadIdx.x * 4] = pk;
}

extern "C" void kernel_launch(void* const* d_in, const int* in_sizes, int n_in,
                              void* d_out, int out_size, void* d_ws, size_t ws_size,
                              hipStream_t stream)
{
  const int*   inputs     = (const int*)d_in[0];
  const int*   dependency = (const int*)d_in[1];
  const float* embed      = (const float*)d_in[2];
  const float* dept       = (const float*)d_in[3];
  const float* Wq = (const float*)d_in[4];   const float* bq = (const float*)d_in[5];
  const float* Wk = (const float*)d_in[6];   const float* bk = (const float*)d_in[7];
  const float* Wv = (const float*)d_in[8];   const float* bvv = (const float*)d_in[9];
  const float* W1 = (const float*)d_in[10];  const float* b1 = (const float*)d_in[11];
  const float* W2 = (const float*)d_in[12];  const float* b2 = (const float*)d_in[13];

  float* out  = (float*)d_out;                       // wm [16,1024,512] fp32 (32 MB)
  float* wout = out + (size_t)8388608;               // weights [16,1024,1024] fp32 (64 MB)

  // ws (shorts), high-water 36.2 MB (same as the round-3 pass):
  //  [0 .. 8388608)        q          -> wbf lo -> h
  //  [8388608 .. 16777216) kx         -> wbf hi
  //  [16777216 .. )        WTcat(3x) W1T W2T  (end 18087936)
  unsigned short* ws   = (unsigned short*)d_ws;
  unsigned short* q    = ws;
  unsigned short* kx   = ws + 8388608;
  unsigned short* WTc  = ws + 16777216;
  unsigned short* W1T  = ws + 17563648;
  unsigned short* W2T  = ws + 17825792;
  unsigned short* wbf  = ws;                          // [16384,1024] bf16 (32 MB)
  unsigned short* h    = ws;                          // [16384,512] bf16

  // output regions used as staging (dead before final writes):
  unsigned short* x    = (unsigned short*)wout;       // [16384,512] bf16; E overwrites later
  unsigned short* v    = (unsigned short*)out;        // [16384,512] bf16 in wm region lo
  unsigned short* vT   = (unsigned short*)out + 8388608;  // [16,512,1024] bf16 in wm hi
  unsigned short* wmp  = (unsigned short*)out;        // [16384,512] bf16 (over dead v)

  dim3 blk(256);

  trans_w<<<dim3(16, 16, 5), blk, 0, stream>>>(Wq, Wk, Wv, W1, W2, WTc);
  build_x<<<dim3(4096), blk, 0, stream>>>(embed, inputs, x);

  gemm_qkv<<<dim3(12, 128, 1), blk, 0, stream>>>(x, WTc, bq, bk, bvv, q, kx, v);

  score_kernel<<<dim3(8, 8, 16), blk, 0, stream>>>(q, kx, dependency, dept, wout);

  trans_v<<<dim3(16, 32, 16), blk, 0, stream>>>(v, vT);

  normalize_rows<<<dim3(16384), blk, 0, stream>>>(wout, wbf);

  // wm_pre = weights @ v   (bf16 x bf16, batched)
  gemm2<0, 0><<<dim3(4, 8, 16), blk, 0, stream>>>(wbf, vT, nullptr, wmp,
                                                  512, 1024, 1024L * 1024, 512L * 1024, 1024L * 512);
  // h = tanh(wm_pre @ W1^T + b1)
  gemm2<0, 1><<<dim3(4, 128, 1), blk, 0, stream>>>(wmp, W1T, b1, h, 512, 512, 0, 0, 0);
  // wm = h @ W2^T + b2  (fp32, overwrites wmp/vT staging -- both dead)
  gemm2<1, 0><<<dim3(4, 128, 1), blk, 0, stream>>>(h, W2T, b2, out, 512, 512, 0, 0, 0);
}